// Round 5
// baseline (121.622 us; speedup 1.0000x reference)
//
#include <hip/hip_runtime.h>

typedef float f32x16 __attribute__((ext_vector_type(16)));
typedef float f32x4  __attribute__((ext_vector_type(4)));
typedef float f32x2  __attribute__((ext_vector_type(2)));
typedef short bf16x8 __attribute__((ext_vector_type(8)));

#define NB 16
#define CI 64
#define CO 64
#define Hh 128
#define Ww 128

// A in 32x32x16-fragment order: short index ((tap*4+ks)*8 + mg)*512 + l*8 + e
// M-remap (px in-lane): m = mg*32 + r ; py = mg>>2, och = mg&3, oc = och*16 + (r>>1), px = r&1
// k: ic = ks*16 + (l>>5)*8 + e
__device__ short g_A[9 * 4 * 8 * 64 * 8];            // 288 KB
__device__ short g_xh[(size_t)NB * Hh * Ww * CI];    // x in NHWC bf16, 33.5 MB

__device__ inline short f2bf(float f) {
  union { float f; unsigned u; } v; v.f = f;
  unsigned r = (v.u + 0x7FFF + ((v.u >> 16) & 1)) >> 16;   // RNE
  return (short)r;
}

// Merged prep: blocks [0,2048) = NCHW fp32 -> NHWC bf16 transpose; [2048,2112) = filters.
__global__ __launch_bounds__(256) void prep(const float* __restrict__ x,
                                            const float* __restrict__ w) {
  const int tid = threadIdx.x;
  if (blockIdx.x >= 2048) {
    const int base = (blockIdx.x - 2048) * 2304;
    #pragma unroll
    for (int i = 0; i < 9; ++i) {
      const int ef = base + i * 256 + tid;
      const int e   = ef & 7;
      const int l   = (ef >> 3) & 63;
      const int mg  = (ef >> 9) & 7;
      const int ks  = (ef >> 12) & 3;
      const int tap = ef >> 14;
      const int r   = l & 31;
      const int px  = r & 1;
      const int py  = mg >> 2;
      const int oc  = (mg & 3) * 16 + (r >> 1);
      const int ic  = ks * 16 + (l >> 5) * 8 + e;
      const int dyi = tap / 3, dxi = tap % 3;
      const int my = 2 * dyi + 1 - py;      // composite 6-tap index for this parity
      const int mx = 2 * dxi + 1 - px;
      const float FF[4] = {0.25f, 0.75f, 0.75f, 0.25f}; // [1,3,3,1]/4 incl. up^2 gain
      const float* wp = w + (oc * CI + ic) * 9;
      float s = 0.f;
      #pragma unroll
      for (int ky = 0; ky < 3; ++ky) {
        const int iy = my - ky;
        if (iy < 0 || iy > 3) continue;
        #pragma unroll
        for (int kx = 0; kx < 3; ++kx) {
          const int ix = mx - kx;
          if (ix < 0 || ix > 3) continue;
          s += wp[(2 - ky) * 3 + (2 - kx)] * (FF[iy] * FF[ix]); // true conv: flipped w
        }
      }
      g_A[ef] = f2bf(s * (1.0f / 24.0f));   // WEIGHT_GAIN = 1/sqrt(64*9)
    }
    return;
  }
  // ---- NCHW -> NHWC via LDS transpose, coalesced both sides ----
  __shared__ alignas(16) char xt[64 * 512];          // 32 KB fp32, XOR-granule swizzle
  const int b = blockIdx.x;                 // (n, y)
  const int n = b >> 7, y = b & 127;
  #pragma unroll
  for (int it = 0; it < 8; ++it) {
    const int idx = tid + it * 256;         // 0..2047 float4 units
    const int ic = idx >> 5, xq = idx & 31;
    const f32x4 v = *(const f32x4*)(x + (((size_t)n * CI + ic) * Hh + y) * Ww + xq * 4);
    *(f32x4*)(xt + ic * 512 + ((xq * 16) ^ (((ic >> 3) & 7) * 16))) = v;
  }
  __syncthreads();
  #pragma unroll
  for (int it = 0; it < 4; ++it) {
    const int idx = tid + it * 256;         // 0..1023
    const int icb = idx & 7, xp = idx >> 3; // xp 0..127
    bf16x8 o;
    #pragma unroll
    for (int j = 0; j < 8; ++j) {
      const int ic = icb * 8 + j;
      const float f = *(const float*)(xt + ic * 512 + (((xp >> 2) * 16) ^ (icb * 16)) + (xp & 3) * 4);
      o[j] = f2bf(f);
    }
    *(bf16x8*)(g_xh + (((size_t)n * Hh + y) * Ww + xp) * CI + icb * 8) = o;
  }
}

// Main conv: block = 256 thr (4 waves), M=256 x N=64 (16p x 4q pos tile), halo 6x18.
// Wave = 2 distinct mg (M64) x nf2 (N64) -> no A duplication across waves.
#define CH_STR 1728   // 108 pix * 16 B  (= 432 dwords == 16 mod 32 -> uniform bank skew)

__global__ __launch_bounds__(256, 3) void mfma_conv(const float* __restrict__ bias,
                                                    float* __restrict__ out) {
  __shared__ alignas(16) char xs[8 * CH_STR];        // 13824 B

  const int tid = threadIdx.x;
  const int l   = tid & 63;
  const int wid = tid >> 6;                 // 4 waves; wave covers mg {2*wid, 2*wid+1}
  const int n   = blockIdx.y;
  const int ty0 = blockIdx.x >> 3, tx0 = blockIdx.x & 7;
  const int qb  = ty0 * 4, pb = tx0 * 16;

  // ---- issue tap-0 A-fragment loads (L2-resident, coalesced 1KB per fragment) ----
  bf16x8 a[4][2];                           // [ks][mf]
  #pragma unroll
  for (int ks = 0; ks < 4; ++ks)
    #pragma unroll
    for (int mf = 0; mf < 2; ++mf)
      a[ks][mf] = *(const bf16x8*)(g_A + (ks * 8 + wid * 2 + mf) * 512 + l * 8);

  // ---- stage 6x18x64 halo into chunked LDS ----
  const size_t xbase = (size_t)n * (Hh * Ww * CI);
  for (int u = tid; u < 864; u += 256) {    // 108 pix * 8 chunks
    const int icb8 = u & 7, pix = u >> 3;
    const int yy = pix / 18, xx = pix - yy * 18;
    const int gy = qb - 1 + yy, gx = pb - 1 + xx;
    bf16x8 v = {};
    if ((unsigned)gy < (unsigned)Hh && (unsigned)gx < (unsigned)Ww)
      v = *(const bf16x8*)(g_xh + xbase + (size_t)(gy * Ww + gx) * CI + icb8 * 8);
    *(bf16x8*)(xs + icb8 * CH_STR + pix * 16) = v;
  }
  __syncthreads();                          // the only barrier

  f32x16 acc[2][2];
  #pragma unroll
  for (int mf = 0; mf < 2; ++mf)
    #pragma unroll
    for (int nf = 0; nf < 2; ++nf)
      #pragma unroll
      for (int r = 0; r < 16; ++r) acc[mf][nf][r] = 0.f;

  const int col = l & 31, kg2 = l >> 5;
  const int p = col & 15, qh = col >> 4;    // pos = nf*32 + col -> q = nf*2+qh, p
  int bbase[2];
  #pragma unroll
  for (int nf = 0; nf < 2; ++nf)
    bbase[nf] = kg2 * CH_STR + ((nf * 2 + qh) * 18 + p) * 16;

  #pragma unroll
  for (int tap = 0; tap < 9; ++tap) {
    const int dyi = tap / 3, dxi = tap % 3;
    const int bsh = (dyi * 18 + dxi) * 16;
    #pragma unroll
    for (int ks = 0; ks < 4; ++ks) {
      bf16x8 b[2];
      #pragma unroll
      for (int nf = 0; nf < 2; ++nf)
        b[nf] = *(const bf16x8*)(xs + bbase[nf] + ks * (2 * CH_STR) + bsh);
      __builtin_amdgcn_s_setprio(1);
      #pragma unroll
      for (int mf = 0; mf < 2; ++mf)
        #pragma unroll
        for (int nf = 0; nf < 2; ++nf)
          acc[mf][nf] = __builtin_amdgcn_mfma_f32_32x32x16_bf16(a[ks][mf], b[nf], acc[mf][nf], 0, 0, 0);
      __builtin_amdgcn_s_setprio(0);
      if (tap < 8) {                        // reload a[ks] for tap+1 (regs just freed)
        #pragma unroll
        for (int mf = 0; mf < 2; ++mf)
          a[ks][mf] = *(const bf16x8*)(g_A + (((tap + 1) * 4 + ks) * 8 + wid * 2 + mf) * 512 + l * 8);
      }
    }
  }

  // ---- epilogue: bias + lrelu*sqrt2 + clamp; in-lane px pairs -> dense f32x2 nt stores ----
  float* outp = out + ((size_t)(n * CO) << 16);
  #pragma unroll
  for (int mf = 0; mf < 2; ++mf) {
    const int mg = wid * 2 + mf;
    const int py = mg >> 2, och = mg & 3;
    #pragma unroll
    for (int nf = 0; nf < 2; ++nf) {
      const int q = nf * 2 + qh;
      const int y = 2 * (qb + q) + py;
      const int xd = 2 * (pb + p);
      #pragma unroll
      for (int rp = 0; rp < 8; ++rp) {
        const int oc = och * 16 + (rp & 1) + 4 * (rp >> 1) + 2 * kg2;
        const float bj = bias[oc];
        float v0 = acc[mf][nf][2 * rp]     + bj;
        float v1 = acc[mf][nf][2 * rp + 1] + bj;
        v0 = (v0 >= 0.f ? v0 : 0.2f * v0) * 1.4142135623730951f;
        v1 = (v1 >= 0.f ? v1 : 0.2f * v1) * 1.4142135623730951f;
        v0 = fminf(256.f, fmaxf(-256.f, v0));
        v1 = fminf(256.f, fmaxf(-256.f, v1));
        f32x2 o; o[0] = v0; o[1] = v1;
        __builtin_nontemporal_store(o, (f32x2*)(outp + ((size_t)oc << 16) + y * 256 + xd));
      }
    }
  }
}

extern "C" void kernel_launch(void* const* d_in, const int* in_sizes, int n_in,
                              void* d_out, int out_size, void* d_ws, size_t ws_size,
                              hipStream_t stream) {
  const float* x    = (const float*)d_in[0];
  const float* w    = (const float*)d_in[1];
  const float* bias = (const float*)d_in[2];
  float* out = (float*)d_out;

  prep<<<2112, 256, 0, stream>>>(x, w);
  mfma_conv<<<dim3(256, NB), 256, 0, stream>>>(bias, out);
}